// Round 6
// baseline (184.087 us; speedup 1.0000x reference)
//
#include <hip/hip_runtime.h>

// Problem constants (fixed by reference: B=32,D=64,H=32,W=32,K=2048)
#define N_PIX 32768   // B*H*W
#define DIM   64
#define KCODE 2048

typedef __attribute__((ext_vector_type(8))) short bf16x8;   // 8 bf16 = 4 VGPR
typedef __attribute__((ext_vector_type(4))) float f32x4;    // MFMA C/D

// bf16 round-to-nearest-even (manual, deterministic)
__device__ inline unsigned short f2bf(float v) {
    unsigned int u = __float_as_uint(v);
    return (unsigned short)((u + 0x7FFFu + ((u >> 16) & 1u)) >> 16);
}
__device__ inline float bf2f(unsigned short b) {
    return __uint_as_float(((unsigned int)b) << 16);
}

// ---------------------------------------------------------------------------
// convert_b: split codebook into 3 bf16 planes (fragment-major 256B units
// [n 0..15][j 0..7]) + e_sq. 8 blocks x 256 thr. e = h+m+l, err ~2^-27|e|.
// ---------------------------------------------------------------------------
__global__ __launch_bounds__(256)
void convert_b_kernel(const float* __restrict__ cb, unsigned short* __restrict__ Bg,
                      float* __restrict__ esq) {
    const int n = blockIdx.x * 256 + threadIdx.x;   // code id 0..2047
    const float* src = cb + (size_t)n * DIM;
    const int ntile = n >> 4, ni = n & 15;
    char* outb = (char*)Bg;
    float s = 0.f;
#pragma unroll
    for (int kb = 0; kb < 8; ++kb) {
        alignas(16) unsigned short hv[8], mv[8], lv[8];
#pragma unroll
        for (int j = 0; j < 8; ++j) {
            float v = src[kb * 8 + j];
            s = fmaf(v, v, s);
            unsigned short h = f2bf(v);
            float r1 = v - bf2f(h);
            unsigned short m = f2bf(r1);
            unsigned short l = f2bf(r1 - bf2f(m));
            hv[j] = h; mv[j] = m; lv[j] = l;
        }
        size_t u = ((((size_t)ntile) * 8 + kb) << 8) + ni * 16;
        *(uint4*)(outb + u)          = *(uint4*)hv;      // plane stride 256 KB
        *(uint4*)(outb + 262144 + u) = *(uint4*)mv;
        *(uint4*)(outb + 524288 + u) = *(uint4*)lv;
    }
    esq[n] = s;
}

// ---------------------------------------------------------------------------
// Fused dist+argmin+gather. Grid 512 (2 blocks/CU), block 256 = 2x2 waves.
// Block owns 64 px x ALL 2048 codes (no cross-block merge needed).
//   - A (64px) converted IN-KERNEL, staged to LDS fragment-major, read ONCE
//     into af[3][2][2] = 48 VGPR/thread (small enough to survive the
//     allocator — r5's 96-VGPR af spilled), then A region is reused as the
//     B tile buffer (LDS stays 56 KB -> 2 blocks/CU, m114 barrier overlap).
//   - 16 iters x 128 codes: B tile (48 KB pre-split bf16) register-prefetched
//     (pf[12]) one iter ahead; loads fly during the 96 MFMAs.
//   - 6 bf16 MFMA passes (hl,lh,mm,hm,mh,hh small->large): exact to ~2^-35.
//   - Per-wave: 24 ds_read_b128 per 96 MFMAs (B amortized over 2 mtiles).
//   - Argmin: per-lane running best (n ascending -> strict <), shfl-16
//     col-reduce, LDS wn-pair reduce, lex (d,idx) = numpy first-min.
// ---------------------------------------------------------------------------
__global__ __launch_bounds__(256, 2)
void dist_fused_kernel(const float* __restrict__ laten,
                       const unsigned short* __restrict__ Bg,
                       const float* __restrict__ esq,
                       const float* __restrict__ cb,
                       float* __restrict__ out0, float* __restrict__ out1) {
    __shared__ char  Bs[49152];     // B tile; aliases A staging + reduction scratch
    __shared__ float esqS[2048];    // 8 KB

    const int tid  = threadIdx.x;
    const int lane = tid & 63, wave = tid >> 6;
    const int wm = wave & 1, wn = wave >> 1;         // 2 x 2 wave grid
    const int quad = lane >> 4, col = lane & 15;
    const int bx = blockIdx.x;
    const int bb = bx >> 4, hw0 = (bx & 15) * 64;    // 64 px contiguous in hw

    // ---- issue B tile-0 prefetch (48 KB / 256 thr = 12 x uint4) ----
    const char* BgB = (const char*)Bg;
    uint4 pf[12];
#pragma unroll
    for (int i = 0; i < 12; ++i) {
        int c = tid + i * 256, pl = c >> 10, r = c & 1023;
        pf[i] = *(const uint4*)(BgB + (size_t)pl * 262144 + r * 16);
    }

    // ---- stage A: load 16 fp32 dims of pixel (tid&63), split, LDS frag-major
    {
        const int p = tid & 63, dg = tid >> 6;       // dg 0..3 = 16 dims each
        const float* srcA = laten + (size_t)bb * 65536 + (size_t)dg * 16384 + hw0 + p;
        const int mt = p >> 4, mi = p & 15;
#pragma unroll
        for (int half = 0; half < 2; ++half) {       // kb = dg*2 + half
            alignas(16) unsigned short hv[8], mv[8], lv[8];
#pragma unroll
            for (int j = 0; j < 8; ++j) {
                float v = srcA[(size_t)(half * 8 + j) << 10];   // coalesced
                unsigned short h = f2bf(v);
                float r1 = v - bf2f(h);
                unsigned short m = f2bf(r1);
                unsigned short l = f2bf(r1 - bf2f(m));
                hv[j] = h; mv[j] = m; lv[j] = l;
            }
            int u = ((mt * 8 + dg * 2 + half) << 8) + mi * 16;
            *(uint4*)(Bs + u)         = *(uint4*)hv;            // plane h [0,8K)
            *(uint4*)(Bs + 8192 + u)  = *(uint4*)mv;            // plane m
            *(uint4*)(Bs + 16384 + u) = *(uint4*)lv;            // plane l
        }
    }
    // stage e_sq (8 floats/thread)
    {
        float4 e0 = *(const float4*)(esq + tid * 8);
        float4 e1 = *(const float4*)(esq + tid * 8 + 4);
        *(float4*)(esqS + tid * 8)     = e0;
        *(float4*)(esqS + tid * 8 + 4) = e1;
    }
    __syncthreads();

    // ---- A fragments -> VGPRs (once; 48 VGPR total) ----
    bf16x8 af[3][2][2];
#pragma unroll
    for (int pl = 0; pl < 3; ++pl)
#pragma unroll
        for (int mt = 0; mt < 2; ++mt)
#pragma unroll
            for (int ks = 0; ks < 2; ++ks)
                af[pl][mt][ks] = *(const bf16x8*)(Bs + pl * 8192
                    + (((wm * 2 + mt) * 8 + ks * 4 + quad) << 8) + col * 16);
    __syncthreads();   // all waves' af reads drained -> Bs reusable for B tiles

    float best[2][4];
    int   bidx[2][4];
#pragma unroll
    for (int mt = 0; mt < 2; ++mt)
#pragma unroll
        for (int r = 0; r < 4; ++r) { best[mt][r] = 3.4e38f; bidx[mt][r] = 0; }

    for (int it = 0; it < 16; ++it) {
        // commit tile it (pf loaded last iter / pre-loop; vmcnt wait implicit)
#pragma unroll
        for (int i = 0; i < 12; ++i) { int c = tid + i * 256; *(uint4*)(Bs + c * 16) = pf[i]; }
        __syncthreads();

        // issue next tile's loads now; they fly during the MFMAs
        if (it < 15) {
#pragma unroll
            for (int i = 0; i < 12; ++i) {
                int c = tid + i * 256, pl = c >> 10, r = c & 1023;
                pf[i] = *(const uint4*)(BgB + (size_t)pl * 262144
                                        + (size_t)(it + 1) * 16384 + r * 16);
            }
        }

        f32x4 acc[2][4];
#pragma unroll
        for (int mt = 0; mt < 2; ++mt)
#pragma unroll
            for (int nt = 0; nt < 4; ++nt) acc[mt][nt] = {0.f, 0.f, 0.f, 0.f};

#pragma unroll
        for (int ntp = 0; ntp < 2; ++ntp) {
            bf16x8 bfr[3][2][2];   // [pl][nt][ks] for this nt-pair
#pragma unroll
            for (int pl = 0; pl < 3; ++pl)
#pragma unroll
                for (int nt = 0; nt < 2; ++nt)
#pragma unroll
                    for (int ks = 0; ks < 2; ++ks)
                        bfr[pl][nt][ks] = *(const bf16x8*)(Bs + pl * 16384
                            + (((wn * 4 + ntp * 2 + nt) * 8 + ks * 4 + quad) << 8)
                            + col * 16);
            const int paArr[6] = {0, 2, 1, 0, 1, 0};   // small->large passes
            const int pbArr[6] = {2, 0, 1, 1, 0, 0};
#pragma unroll
            for (int pass = 0; pass < 6; ++pass)
#pragma unroll
                for (int ks = 0; ks < 2; ++ks)
#pragma unroll
                    for (int mt = 0; mt < 2; ++mt)
#pragma unroll
                        for (int nt = 0; nt < 2; ++nt)   // 4 indep MFMAs/group
                            acc[mt][ntp * 2 + nt] = __builtin_amdgcn_mfma_f32_16x16x32_bf16(
                                af[paArr[pass]][mt][ks], bfr[pbArr[pass]][nt][ks],
                                acc[mt][ntp * 2 + nt], 0, 0, 0);
        }

        // running argmin; per-(lane,mt,r) n strictly ascends -> strict <
#pragma unroll
        for (int nt = 0; nt < 4; ++nt) {
            const int n = it * 128 + wn * 64 + nt * 16 + col;
            const float e = esqS[n];
#pragma unroll
            for (int mt = 0; mt < 2; ++mt)
#pragma unroll
                for (int r = 0; r < 4; ++r) {
                    float d = fmaf(-2.f, acc[mt][nt][r], e);
                    if (d < best[mt][r]) { best[mt][r] = d; bidx[mt][r] = n; }
                }
        }
        __syncthreads();   // all Bs reads done -> next commit safe
    }

    // ---- reduce: shfl over 16 cols, then LDS over the wn pair ----
    float* redD = (float*)Bs;            // [64][2]
    int*   redI = (int*)(Bs + 512);      // [64][2]
    int*   idxF = (int*)(Bs + 1024);     // [64]
#pragma unroll
    for (int mt = 0; mt < 2; ++mt)
#pragma unroll
        for (int r = 0; r < 4; ++r) {
            float d = best[mt][r];
            int   i = bidx[mt][r];
#pragma unroll
            for (int m = 1; m < 16; m <<= 1) {
                float od = __shfl_xor(d, m, 16);
                int   oi = __shfl_xor(i, m, 16);
                if (od < d || (od == d && oi < i)) { d = od; i = oi; }
            }
            if (col == 0) {
                int row = wm * 32 + mt * 16 + quad * 4 + r;   // pixel in block
                redD[row * 2 + wn] = d;
                redI[row * 2 + wn] = i;
            }
        }
    __syncthreads();

    if (tid < 64) {
        float d0 = redD[tid * 2], d1 = redD[tid * 2 + 1];
        int   i0 = redI[tid * 2], i1 = redI[tid * 2 + 1];
        int bi = (d1 < d0 || (d1 == d0 && i1 < i0)) ? i1 : i0;
        out0[bx * 64 + tid] = (float)bi;
        idxF[tid] = bi;
    }
    __syncthreads();

    // ---- fused gather: 64 px x 64 dims from the ORIGINAL fp32 codebook ----
    const int p = tid & 63, dg = tid >> 6;
    const int idx = idxF[p];
    const float4* srcr = (const float4*)(cb + ((size_t)idx << 6) + dg * 16);
    float* o = out1 + (size_t)bb * 65536 + (size_t)dg * 16384 + hw0 + p;
#pragma unroll
    for (int q = 0; q < 4; ++q) {
        float4 v = srcr[q];
        o[(size_t)(q * 4 + 0) << 10] = v.x;
        o[(size_t)(q * 4 + 1) << 10] = v.y;
        o[(size_t)(q * 4 + 2) << 10] = v.z;
        o[(size_t)(q * 4 + 3) << 10] = v.w;
    }
}

// ---------------------------------------------------------------------------
extern "C" void kernel_launch(void* const* d_in, const int* in_sizes, int n_in,
                              void* d_out, int out_size, void* d_ws, size_t ws_size,
                              hipStream_t stream) {
    const float* laten = (const float*)d_in[0];   // (32,64,32,32) fp32
    const float* cb    = (const float*)d_in[1];   // (2048,64) fp32

    float* out0 = (float*)d_out;                  // indices as float, N_PIX
    float* out1 = (float*)d_out + N_PIX;          // quant_laten, 2M

    // ws layout: esq 8 KB | Bg 768 KB   (~776 KB total)
    float* esq = (float*)d_ws;
    unsigned short* Bg = (unsigned short*)(esq + 2048);

    convert_b_kernel<<<8, 256, 0, stream>>>(cb, Bg, esq);

    dist_fused_kernel<<<512, 256, 0, stream>>>(laten, Bg, esq, cb, out0, out1);
}

// Round 7
// 142.494 us; speedup vs baseline: 1.2919x; 1.2919x over previous
//
#include <hip/hip_runtime.h>

// Problem constants (fixed by reference: B=32,D=64,H=32,W=32,K=2048)
#define N_PIX 32768   // B*H*W
#define DIM   64
#define KCODE 2048

typedef __attribute__((ext_vector_type(8))) short bf16x8;   // 8 bf16 = 4 VGPR
typedef __attribute__((ext_vector_type(4))) float f32x4;    // MFMA C/D

// bf16 round-to-nearest-even (manual, deterministic)
__device__ inline unsigned short f2bf(float v) {
    unsigned int u = __float_as_uint(v);
    return (unsigned short)((u + 0x7FFFu + ((u >> 16) & 1u)) >> 16);
}
__device__ inline float bf2f(unsigned short b) {
    return __uint_as_float(((unsigned int)b) << 16);
}

// ---------------------------------------------------------------------------
// convert_b: split codebook into 3 bf16 planes (fragment-major 256B units
// [n 0..15][j 0..7]) + e_sq. 8 blocks x 256 thr. e = h+m+l, err ~2^-27|e|.
// ---------------------------------------------------------------------------
__global__ __launch_bounds__(256)
void convert_b_kernel(const float* __restrict__ cb, unsigned short* __restrict__ Bg,
                      float* __restrict__ esq) {
    const int n = blockIdx.x * 256 + threadIdx.x;   // code id 0..2047
    const float* src = cb + (size_t)n * DIM;
    const int ntile = n >> 4, ni = n & 15;
    char* outb = (char*)Bg;
    float s = 0.f;
#pragma unroll
    for (int kb = 0; kb < 8; ++kb) {
        alignas(16) unsigned short hv[8], mv[8], lv[8];
#pragma unroll
        for (int j = 0; j < 8; ++j) {
            float v = src[kb * 8 + j];
            s = fmaf(v, v, s);
            unsigned short h = f2bf(v);
            float r1 = v - bf2f(h);
            unsigned short m = f2bf(r1);
            unsigned short l = f2bf(r1 - bf2f(m));
            hv[j] = h; mv[j] = m; lv[j] = l;
        }
        size_t u = ((((size_t)ntile) * 8 + kb) << 8) + ni * 16;
        *(uint4*)(outb + u)          = *(uint4*)hv;      // plane stride 256 KB
        *(uint4*)(outb + 262144 + u) = *(uint4*)mv;
        *(uint4*)(outb + 524288 + u) = *(uint4*)lv;
    }
    esq[n] = s;
}

// MFMA pass with LITERAL plane indices -> af/bfr/acc always constant-indexed
// (r5/r6 lesson: SROA runs before unrolling; array[array[i]] => scratch).
#define DO_PASS(APL, BPL)                                                    \
    _Pragma("unroll") for (int ks = 0; ks < 2; ++ks)                         \
    _Pragma("unroll") for (int mt = 0; mt < 2; ++mt)                         \
    _Pragma("unroll") for (int nt = 0; nt < 2; ++nt)                         \
        acc[mt][nt] = __builtin_amdgcn_mfma_f32_16x16x32_bf16(               \
            af[APL][mt][ks], bfr[BPL][nt][ks], acc[mt][nt], 0, 0, 0);

// ---------------------------------------------------------------------------
// Fused dist+argmin+gather. Grid 512 (2 blocks/CU), block 256 = 2x2 waves.
// Block owns 64 px x ALL 2048 codes; 32 iters x 64-code tiles, double-
// buffered LDS (Bs0/Bs1, separate decls), pf-register prefetch issued before
// the MFMA block (in flight during compute), committed after, 1 barrier/iter.
//   - af[3][2][2] = 48 VGPR resident; ALL local arrays constant-indexed.
//   - 6 bf16 passes (hl,lh,mm,hm,mh,hh small->large): exact to ~2^-35.
//   - argmin: per-lane running best (n ascending -> strict <), shfl-16
//     col-reduce, LDS wn-pair reduce, lex (d,idx) = numpy first-min.
// ---------------------------------------------------------------------------
__global__ __launch_bounds__(256, 2)
void dist_fused_kernel(const float* __restrict__ laten,
                       const unsigned short* __restrict__ Bg,
                       const float* __restrict__ esq,
                       const float* __restrict__ cb,
                       float* __restrict__ out0, float* __restrict__ out1) {
    __shared__ char  Bs0[24576];    // B tile buffer A (also reduction scratch)
    __shared__ char  Bs1[24576];    // B tile buffer B (also A-staging area)
    __shared__ float esqS[2048];    // 8 KB

    const int tid  = threadIdx.x;
    const int lane = tid & 63, wave = tid >> 6;
    const int wm = wave & 1, wn = wave >> 1;         // 2 x 2 wave grid
    const int quad = lane >> 4, col = lane & 15;
    const int bx = blockIdx.x;
    const int bb = bx >> 4, hw0 = (bx & 15) * 64;    // 64 px contiguous in hw

    const char* BgB = (const char*)Bg;

    // ---- issue tile-0 loads into pf regs (constant-trip: SROA-safe) ----
    uint4 pf[6];
#pragma unroll
    for (int i = 0; i < 6; ++i)
        pf[i] = *(const uint4*)(BgB + (size_t)(i >> 1) * 262144
                                + (tid + (i & 1) * 256) * 16);

    // ---- stage A into Bs1: 16 fp32 dims of pixel (tid&63), 3-way split ----
    {
        const int p = tid & 63, dg = tid >> 6;       // dg 0..3 = 16 dims each
        const float* srcA = laten + (size_t)bb * 65536 + (size_t)dg * 16384 + hw0 + p;
        const int mt = p >> 4, mi = p & 15;
#pragma unroll
        for (int half = 0; half < 2; ++half) {       // kb = dg*2 + half
            alignas(16) unsigned short hv[8], mv[8], lv[8];
#pragma unroll
            for (int j = 0; j < 8; ++j) {
                float v = srcA[(size_t)(half * 8 + j) << 10];   // coalesced
                unsigned short h = f2bf(v);
                float r1 = v - bf2f(h);
                unsigned short m = f2bf(r1);
                unsigned short l = f2bf(r1 - bf2f(m));
                hv[j] = h; mv[j] = m; lv[j] = l;
            }
            int u = ((mt * 8 + dg * 2 + half) << 8) + mi * 16;
            *(uint4*)(Bs1 + u)         = *(uint4*)hv;           // plane h
            *(uint4*)(Bs1 + 8192 + u)  = *(uint4*)mv;           // plane m
            *(uint4*)(Bs1 + 16384 + u) = *(uint4*)lv;           // plane l
        }
    }
    // stage e_sq (8 floats/thread)
    {
        float4 e0 = *(const float4*)(esq + tid * 8);
        float4 e1 = *(const float4*)(esq + tid * 8 + 4);
        *(float4*)(esqS + tid * 8)     = e0;
        *(float4*)(esqS + tid * 8 + 4) = e1;
    }
    __syncthreads();

    // ---- A fragments -> VGPRs (once; 48 VGPR, constant-indexed) ----
    bf16x8 af[3][2][2];
#pragma unroll
    for (int pl = 0; pl < 3; ++pl)
#pragma unroll
        for (int mt = 0; mt < 2; ++mt)
#pragma unroll
            for (int ks = 0; ks < 2; ++ks)
                af[pl][mt][ks] = *(const bf16x8*)(Bs1 + pl * 8192
                    + (((wm * 2 + mt) * 8 + ks * 4 + quad) << 8) + col * 16);

    // commit tile 0 into Bs0 (pf regs free after; doesn't touch Bs1)
#pragma unroll
    for (int i = 0; i < 6; ++i)
        *(uint4*)(Bs0 + (tid + i * 256) * 16) = pf[i];
    __syncthreads();   // af reads done in all waves; Bs0 committed

    float best[2][4];
    int   bidx[2][4];
#pragma unroll
    for (int mt = 0; mt < 2; ++mt)
#pragma unroll
        for (int r = 0; r < 4; ++r) { best[mt][r] = 3.4e38f; bidx[mt][r] = 0; }

    for (int it = 0; it < 32; ++it) {
        const char* rb = (it & 1) ? Bs1 : Bs0;       // read tile it
        char*       wb = (it & 1) ? Bs0 : Bs1;       // commit tile it+1

        // issue tile it+1 loads now: in flight during the MFMA block
        if (it < 31) {
#pragma unroll
            for (int i = 0; i < 6; ++i)
                pf[i] = *(const uint4*)(BgB + (size_t)(i >> 1) * 262144
                        + (size_t)(it + 1) * 8192 + (tid + (i & 1) * 256) * 16);
        }

        // B fragments for this tile (48 VGPR transient, constant-indexed)
        bf16x8 bfr[3][2][2];
#pragma unroll
        for (int pl = 0; pl < 3; ++pl)
#pragma unroll
            for (int nt = 0; nt < 2; ++nt)
#pragma unroll
                for (int ks = 0; ks < 2; ++ks)
                    bfr[pl][nt][ks] = *(const bf16x8*)(rb + pl * 8192
                        + (((wn * 2 + nt) * 8 + ks * 4 + quad) << 8) + col * 16);

        f32x4 acc[2][2];
#pragma unroll
        for (int mt = 0; mt < 2; ++mt)
#pragma unroll
            for (int nt = 0; nt < 2; ++nt) acc[mt][nt] = {0.f, 0.f, 0.f, 0.f};

        // 6 passes, small->large (hl, lh, mm, hm, mh, hh) — literal planes
        DO_PASS(0, 2)
        DO_PASS(2, 0)
        DO_PASS(1, 1)
        DO_PASS(0, 1)
        DO_PASS(1, 0)
        DO_PASS(0, 0)

        // running argmin; per-lane n strictly ascends across (it, nt)
#pragma unroll
        for (int nt = 0; nt < 2; ++nt) {
            const int n = it * 64 + (wn * 2 + nt) * 16 + col;
            const float e = esqS[n];
#pragma unroll
            for (int mt = 0; mt < 2; ++mt)
#pragma unroll
                for (int r = 0; r < 4; ++r) {
                    float d = fmaf(-2.f, acc[mt][nt][r], e);
                    if (d < best[mt][r]) { best[mt][r] = d; bidx[mt][r] = n; }
                }
        }

        // commit tile it+1 (other buffer; prev barrier guarantees all waves
        // finished reading it)
        if (it < 31) {
#pragma unroll
            for (int i = 0; i < 6; ++i)
                *(uint4*)(wb + (tid + i * 256) * 16) = pf[i];
        }
        __syncthreads();
    }

    // ---- reduce: shfl over 16 cols, then LDS over the wn pair ----
    float* redD = (float*)Bs0;           // [64][2]
    int*   redI = (int*)(Bs0 + 512);     // [64][2]
    int*   idxF = (int*)(Bs0 + 1024);    // [64]
#pragma unroll
    for (int mt = 0; mt < 2; ++mt)
#pragma unroll
        for (int r = 0; r < 4; ++r) {
            float d = best[mt][r];
            int   i = bidx[mt][r];
#pragma unroll
            for (int m = 1; m < 16; m <<= 1) {
                float od = __shfl_xor(d, m, 16);
                int   oi = __shfl_xor(i, m, 16);
                if (od < d || (od == d && oi < i)) { d = od; i = oi; }
            }
            if (col == 0) {
                int row = (wm * 2 + mt) * 16 + quad * 4 + r;  // pixel in block
                redD[row * 2 + wn] = d;
                redI[row * 2 + wn] = i;
            }
        }
    __syncthreads();

    if (tid < 64) {
        float d0 = redD[tid * 2], d1 = redD[tid * 2 + 1];
        int   i0 = redI[tid * 2], i1 = redI[tid * 2 + 1];
        int bi = (d1 < d0 || (d1 == d0 && i1 < i0)) ? i1 : i0;
        out0[bx * 64 + tid] = (float)bi;
        idxF[tid] = bi;
    }
    __syncthreads();

    // ---- fused gather: 64 px x 64 dims from the ORIGINAL fp32 codebook ----
    const int p = tid & 63, dg = tid >> 6;
    const int idx = idxF[p];
    const float4* srcr = (const float4*)(cb + ((size_t)idx << 6) + dg * 16);
    float* o = out1 + (size_t)bb * 65536 + (size_t)dg * 16384 + hw0 + p;
#pragma unroll
    for (int q = 0; q < 4; ++q) {
        float4 v = srcr[q];
        o[(size_t)(q * 4 + 0) << 10] = v.x;
        o[(size_t)(q * 4 + 1) << 10] = v.y;
        o[(size_t)(q * 4 + 2) << 10] = v.z;
        o[(size_t)(q * 4 + 3) << 10] = v.w;
    }
}

// ---------------------------------------------------------------------------
extern "C" void kernel_launch(void* const* d_in, const int* in_sizes, int n_in,
                              void* d_out, int out_size, void* d_ws, size_t ws_size,
                              hipStream_t stream) {
    const float* laten = (const float*)d_in[0];   // (32,64,32,32) fp32
    const float* cb    = (const float*)d_in[1];   // (2048,64) fp32

    float* out0 = (float*)d_out;                  // indices as float, N_PIX
    float* out1 = (float*)d_out + N_PIX;          // quant_laten, 2M

    // ws layout: esq 8 KB | Bg 768 KB   (~776 KB total)
    float* esq = (float*)d_ws;
    unsigned short* Bg = (unsigned short*)(esq + 2048);

    convert_b_kernel<<<8, 256, 0, stream>>>(cb, Bg, esq);

    dist_fused_kernel<<<512, 256, 0, stream>>>(laten, Bg, esq, cb, out0, out1);
}

// Round 8
// 110.209 us; speedup vs baseline: 1.6703x; 1.2929x over previous
//
#include <hip/hip_runtime.h>

// Problem constants (fixed by reference: B=32,D=64,H=32,W=32,K=2048)
#define N_PIX 32768   // B*H*W
#define DIM   64
#define KCODE 2048

typedef __attribute__((ext_vector_type(8))) short bf16x8;   // 8 bf16 = 4 VGPR
typedef __attribute__((ext_vector_type(4))) float f32x4;    // MFMA C/D

// bf16 round-to-nearest-even (manual, deterministic)
__device__ inline unsigned short f2bf(float v) {
    unsigned int u = __float_as_uint(v);
    return (unsigned short)((u + 0x7FFFu + ((u >> 16) & 1u)) >> 16);
}
__device__ inline float bf2f(unsigned short b) {
    return __uint_as_float(((unsigned int)b) << 16);
}

// ---------------------------------------------------------------------------
// convert_b: split codebook into 3 bf16 planes (fragment-major 256B units
// [n 0..15][j 0..7]) + e_sq. 8 blocks x 256 thr. e = h+m+l, err ~2^-27|e|.
// ---------------------------------------------------------------------------
__global__ __launch_bounds__(256)
void convert_b_kernel(const float* __restrict__ cb, unsigned short* __restrict__ Bg,
                      float* __restrict__ esq) {
    const int n = blockIdx.x * 256 + threadIdx.x;   // code id 0..2047
    const float* src = cb + (size_t)n * DIM;
    const int ntile = n >> 4, ni = n & 15;
    char* outb = (char*)Bg;
    float s = 0.f;
#pragma unroll
    for (int kb = 0; kb < 8; ++kb) {
        alignas(16) unsigned short hv[8], mv[8], lv[8];
#pragma unroll
        for (int j = 0; j < 8; ++j) {
            float v = src[kb * 8 + j];
            s = fmaf(v, v, s);
            unsigned short h = f2bf(v);
            float r1 = v - bf2f(h);
            unsigned short m = f2bf(r1);
            unsigned short l = f2bf(r1 - bf2f(m));
            hv[j] = h; mv[j] = m; lv[j] = l;
        }
        size_t u = ((((size_t)ntile) * 8 + kb) << 8) + ni * 16;
        *(uint4*)(outb + u)          = *(uint4*)hv;      // plane stride 256 KB
        *(uint4*)(outb + 262144 + u) = *(uint4*)mv;
        *(uint4*)(outb + 524288 + u) = *(uint4*)lv;
    }
    esq[n] = s;
}

// MFMA pass with LITERAL plane indices (SROA lesson: no array[array[i]]).
#define DO_PASS(APL, BPL)                                                    \
    _Pragma("unroll") for (int ks = 0; ks < 2; ++ks)                         \
    _Pragma("unroll") for (int mt = 0; mt < 4; ++mt)                         \
    _Pragma("unroll") for (int nt = 0; nt < 2; ++nt)                         \
        acc[mt][nt] = __builtin_amdgcn_mfma_f32_16x16x32_bf16(               \
            af[APL][mt][ks], bfr[BPL][nt][ks], acc[mt][nt], 0, 0, 0);

// ---------------------------------------------------------------------------
// Fused dist+argmin+gather, NO LDS / NO BARRIERS in the main loop.
// Grid 512 (2 blocks/CU), block 256 = 4 waves. Block owns 64 px x all codes.
//   - Every wave holds the FULL 64-px A tile: af[3][4][2] = 96 VGPR,
//     loaded once from an LDS staging pass. Waves split codes 4-ways (wn).
//   - 16 iters x 128 codes: B fragments read DIRECTLY from Bg in L2
//     (coalesced lane*16 dwordx4). Block reads Bg exactly once ->
//     393 MB chip-wide ~12 us of L2 BW, fully overlapped with MFMA.
//     r7 lesson: LDS round-trip for B cost ~as many LDS cycles as MFMA
//     cycles; direct-L2 removes the LDS pipe and all loop barriers.
//   - 6 bf16 passes (hl,lh,mm,hm,mh,hh small->large): exact to ~2^-35.
//   - argmin: per-lane running best (n ascending -> strict <), shfl-16
//     col-reduce, LDS wn-reduce, lex (d,idx) = numpy first-min.
// ---------------------------------------------------------------------------
__global__ __launch_bounds__(256, 2)
void dist_fused_kernel(const float* __restrict__ laten,
                       const unsigned short* __restrict__ Bg,
                       const float* __restrict__ esq,
                       const float* __restrict__ cb,
                       float* __restrict__ out0, float* __restrict__ out1) {
    __shared__ char  As[24576];     // A staging (3 planes x 8 KB); then scratch
    __shared__ float esqS[2048];    // 8 KB

    const int tid  = threadIdx.x;
    const int lane = tid & 63;
    const int wn   = tid >> 6;                       // wave -> code quarter
    const int quad = lane >> 4, col = lane & 15;
    const int bx = blockIdx.x;
    const int bb = bx >> 4, hw0 = (bx & 15) * 64;    // 64 px contiguous in hw

    // ---- stage A into As: 16 fp32 dims of pixel (tid&63), 3-way split ----
    {
        const int p = tid & 63, dg = tid >> 6;       // dg 0..3 = 16 dims each
        const float* srcA = laten + (size_t)bb * 65536 + (size_t)dg * 16384 + hw0 + p;
        const int mt = p >> 4, mi = p & 15;
#pragma unroll
        for (int half = 0; half < 2; ++half) {       // kb = dg*2 + half
            alignas(16) unsigned short hv[8], mv[8], lv[8];
#pragma unroll
            for (int j = 0; j < 8; ++j) {
                float v = srcA[(size_t)(half * 8 + j) << 10];   // coalesced
                unsigned short h = f2bf(v);
                float r1 = v - bf2f(h);
                unsigned short m = f2bf(r1);
                unsigned short l = f2bf(r1 - bf2f(m));
                hv[j] = h; mv[j] = m; lv[j] = l;
            }
            int u = ((mt * 8 + dg * 2 + half) << 8) + mi * 16;
            *(uint4*)(As + u)         = *(uint4*)hv;            // plane h
            *(uint4*)(As + 8192 + u)  = *(uint4*)mv;            // plane m
            *(uint4*)(As + 16384 + u) = *(uint4*)lv;            // plane l
        }
    }
    // stage e_sq (8 floats/thread)
    {
        float4 e0 = *(const float4*)(esq + tid * 8);
        float4 e1 = *(const float4*)(esq + tid * 8 + 4);
        *(float4*)(esqS + tid * 8)     = e0;
        *(float4*)(esqS + tid * 8 + 4) = e1;
    }
    __syncthreads();

    // ---- A fragments -> VGPRs: ALL 4 mtiles per wave (96 VGPR resident) ----
    bf16x8 af[3][4][2];
#pragma unroll
    for (int pl = 0; pl < 3; ++pl)
#pragma unroll
        for (int mt = 0; mt < 4; ++mt)
#pragma unroll
            for (int ks = 0; ks < 2; ++ks)
                af[pl][mt][ks] = *(const bf16x8*)(As + pl * 8192
                    + ((mt * 8 + ks * 4 + quad) << 8) + col * 16);
    __syncthreads();   // all waves done reading As before epilogue reuses it

    float best[4][4];
    int   bidx[4][4];
#pragma unroll
    for (int mt = 0; mt < 4; ++mt)
#pragma unroll
        for (int r = 0; r < 4; ++r) { best[mt][r] = 3.4e38f; bidx[mt][r] = 0; }

    const char* BgB = (const char*)Bg;

    for (int it = 0; it < 16; ++it) {
        // B fragments for this iter: 12 coalesced L2 loads (no LDS, no barrier)
        bf16x8 bfr[3][2][2];
#pragma unroll
        for (int pl = 0; pl < 3; ++pl)
#pragma unroll
            for (int nt = 0; nt < 2; ++nt)
#pragma unroll
                for (int ks = 0; ks < 2; ++ks)
                    bfr[pl][nt][ks] = *(const bf16x8*)(BgB + pl * 262144
                        + (it * 8 + wn * 2 + nt) * 2048 + ks * 1024 + lane * 16);

        f32x4 acc[4][2];
#pragma unroll
        for (int mt = 0; mt < 4; ++mt)
#pragma unroll
            for (int nt = 0; nt < 2; ++nt) acc[mt][nt] = {0.f, 0.f, 0.f, 0.f};

        // 6 passes, small->large (hl, lh, mm, hm, mh, hh) — literal planes
        DO_PASS(0, 2)
        DO_PASS(2, 0)
        DO_PASS(1, 1)
        DO_PASS(0, 1)
        DO_PASS(1, 0)
        DO_PASS(0, 0)

        // running argmin; per-lane n strictly ascends across (it, nt)
#pragma unroll
        for (int nt = 0; nt < 2; ++nt) {
            const int n = it * 128 + wn * 32 + nt * 16 + col;
            const float e = esqS[n];
#pragma unroll
            for (int mt = 0; mt < 4; ++mt)
#pragma unroll
                for (int r = 0; r < 4; ++r) {
                    float d = fmaf(-2.f, acc[mt][nt][r], e);
                    if (d < best[mt][r]) { best[mt][r] = d; bidx[mt][r] = n; }
                }
        }
    }

    // ---- reduce: shfl over 16 cols, then LDS over the 4 wn quarters ----
    float* redD = (float*)As;            // [64][4]
    int*   redI = (int*)(As + 1024);     // [64][4]
    int*   idxF = (int*)(As + 2048);     // [64]
#pragma unroll
    for (int mt = 0; mt < 4; ++mt)
#pragma unroll
        for (int r = 0; r < 4; ++r) {
            float d = best[mt][r];
            int   i = bidx[mt][r];
#pragma unroll
            for (int m = 1; m < 16; m <<= 1) {
                float od = __shfl_xor(d, m, 16);
                int   oi = __shfl_xor(i, m, 16);
                if (od < d || (od == d && oi < i)) { d = od; i = oi; }
            }
            if (col == 0) {
                int row = mt * 16 + quad * 4 + r;    // pixel in block
                redD[row * 4 + wn] = d;
                redI[row * 4 + wn] = i;
            }
        }
    __syncthreads();

    if (tid < 64) {
        float bd = redD[tid * 4]; int bi = redI[tid * 4];
#pragma unroll
        for (int w = 1; w < 4; ++w) {
            float d = redD[tid * 4 + w]; int i = redI[tid * 4 + w];
            if (d < bd || (d == bd && i < bi)) { bd = d; bi = i; }
        }
        out0[bx * 64 + tid] = (float)bi;
        idxF[tid] = bi;
    }
    __syncthreads();

    // ---- fused gather: 64 px x 64 dims from the ORIGINAL fp32 codebook ----
    const int p = tid & 63, dg = tid >> 6;
    const int idx = idxF[p];
    const float4* srcr = (const float4*)(cb + ((size_t)idx << 6) + dg * 16);
    float* o = out1 + (size_t)bb * 65536 + (size_t)dg * 16384 + hw0 + p;
#pragma unroll
    for (int q = 0; q < 4; ++q) {
        float4 v = srcr[q];
        o[(size_t)(q * 4 + 0) << 10] = v.x;
        o[(size_t)(q * 4 + 1) << 10] = v.y;
        o[(size_t)(q * 4 + 2) << 10] = v.z;
        o[(size_t)(q * 4 + 3) << 10] = v.w;
    }
}

// ---------------------------------------------------------------------------
extern "C" void kernel_launch(void* const* d_in, const int* in_sizes, int n_in,
                              void* d_out, int out_size, void* d_ws, size_t ws_size,
                              hipStream_t stream) {
    const float* laten = (const float*)d_in[0];   // (32,64,32,32) fp32
    const float* cb    = (const float*)d_in[1];   // (2048,64) fp32

    float* out0 = (float*)d_out;                  // indices as float, N_PIX
    float* out1 = (float*)d_out + N_PIX;          // quant_laten, 2M

    // ws layout: esq 8 KB | Bg 768 KB   (~776 KB total)
    float* esq = (float*)d_ws;
    unsigned short* Bg = (unsigned short*)(esq + 2048);

    convert_b_kernel<<<8, 256, 0, stream>>>(cb, Bg, esq);

    dist_fused_kernel<<<512, 256, 0, stream>>>(laten, Bg, esq, cb, out0, out1);
}

// Round 9
// 107.928 us; speedup vs baseline: 1.7056x; 1.0211x over previous
//
#include <hip/hip_runtime.h>

// Problem constants (fixed by reference: B=32,D=64,H=32,W=32,K=2048)
#define N_PIX 32768   // B*H*W
#define DIM   64
#define KCODE 2048

typedef __attribute__((ext_vector_type(8))) short bf16x8;   // 8 bf16 = 4 VGPR
typedef __attribute__((ext_vector_type(4))) float f32x4;    // MFMA C/D

// bf16 round-to-nearest-even (manual, deterministic)
__device__ inline unsigned short f2bf(float v) {
    unsigned int u = __float_as_uint(v);
    return (unsigned short)((u + 0x7FFFu + ((u >> 16) & 1u)) >> 16);
}
__device__ inline float bf2f(unsigned short b) {
    return __uint_as_float(((unsigned int)b) << 16);
}

// ---------------------------------------------------------------------------
// convert_b: split codebook into 3 bf16 planes (fragment-major 256B units
// [n 0..15][j 0..7]) + e_sq. 8 blocks x 256 thr. e = h+m+l, err ~2^-27|e|.
// ---------------------------------------------------------------------------
__global__ __launch_bounds__(256)
void convert_b_kernel(const float* __restrict__ cb, unsigned short* __restrict__ Bg,
                      float* __restrict__ esq) {
    const int n = blockIdx.x * 256 + threadIdx.x;   // code id 0..2047
    const float* src = cb + (size_t)n * DIM;
    const int ntile = n >> 4, ni = n & 15;
    char* outb = (char*)Bg;
    float s = 0.f;
#pragma unroll
    for (int kb = 0; kb < 8; ++kb) {
        alignas(16) unsigned short hv[8], mv[8], lv[8];
#pragma unroll
        for (int j = 0; j < 8; ++j) {
            float v = src[kb * 8 + j];
            s = fmaf(v, v, s);
            unsigned short h = f2bf(v);
            float r1 = v - bf2f(h);
            unsigned short m = f2bf(r1);
            unsigned short l = f2bf(r1 - bf2f(m));
            hv[j] = h; mv[j] = m; lv[j] = l;
        }
        size_t u = ((((size_t)ntile) * 8 + kb) << 8) + ni * 16;
        *(uint4*)(outb + u)          = *(uint4*)hv;      // plane stride 256 KB
        *(uint4*)(outb + 262144 + u) = *(uint4*)mv;
        *(uint4*)(outb + 524288 + u) = *(uint4*)lv;
    }
    esq[n] = s;
}

// MFMA pass with LITERAL plane indices (SROA lesson: no array[array[i]]).
#define DO_PASS(APL, BPL)                                                    \
    _Pragma("unroll") for (int ks = 0; ks < 2; ++ks)                         \
    _Pragma("unroll") for (int mt = 0; mt < 4; ++mt)                         \
    _Pragma("unroll") for (int nt = 0; nt < 2; ++nt)                         \
        acc[mt][nt] = __builtin_amdgcn_mfma_f32_16x16x32_bf16(               \
            af[APL][mt][ks], bfr[BPL][nt][ks], acc[mt][nt], 0, 0, 0);

// Load one B plane's 4 fragments for tile IT into bfr[PL] (same regs each
// iter -> zero-register software pipeline; placed right after PL's last use).
#define LOAD_B(PL, IT)                                                       \
    _Pragma("unroll") for (int nt = 0; nt < 2; ++nt)                         \
    _Pragma("unroll") for (int ks = 0; ks < 2; ++ks)                         \
        bfr[PL][nt][ks] = *(const bf16x8*)(BgB + (PL) * 262144               \
            + ((size_t)(IT) * 8 + wn * 2 + nt) * 2048 + ks * 1024 + lane * 16);

// ---------------------------------------------------------------------------
// Fused dist+argmin+gather, no LDS / no barriers in the main loop.
// Grid 512 (2 blocks/CU), block 256 = 4 waves. Block owns 64 px x all codes.
//   - af[3][4][2] = 96 regs resident (whole 64-px A tile per wave);
//     waves split codes 4-ways. B frags read directly from Bg in L2.
//   - r8 lesson: loads-at-top + argmin-at-bottom left ~200 cyc load latency
//     AND the argmin VALU tail exposed every iter (MfmaUtil 38%). Now each
//     plane's next-iter load issues immediately after that plane's last
//     MFMA use (B2 after pass1, B1 after pass4, B0 after pass6), reusing
//     the same registers; argmin sits in the B0-load shadow. Pass order
//     (hl,lh,mm,hm,mh,hh small->large) unchanged -> bit-identical numerics.
//   - argmin: per-lane running best (n ascending -> strict <), shfl-16
//     col-reduce, LDS wn-reduce, lex (d,idx) = numpy first-min.
// ---------------------------------------------------------------------------
__global__ __launch_bounds__(256, 2)
void dist_fused_kernel(const float* __restrict__ laten,
                       const unsigned short* __restrict__ Bg,
                       const float* __restrict__ esq,
                       const float* __restrict__ cb,
                       float* __restrict__ out0, float* __restrict__ out1) {
    __shared__ char  As[24576];     // A staging (3 planes x 8 KB); then scratch
    __shared__ float esqS[2048];    // 8 KB

    const int tid  = threadIdx.x;
    const int lane = tid & 63;
    const int wn   = tid >> 6;                       // wave -> code quarter
    const int quad = lane >> 4, col = lane & 15;
    const int bx = blockIdx.x;
    const int bb = bx >> 4, hw0 = (bx & 15) * 64;    // 64 px contiguous in hw

    // ---- stage A into As: 16 fp32 dims of pixel (tid&63), 3-way split ----
    {
        const int p = tid & 63, dg = tid >> 6;       // dg 0..3 = 16 dims each
        const float* srcA = laten + (size_t)bb * 65536 + (size_t)dg * 16384 + hw0 + p;
        const int mt = p >> 4, mi = p & 15;
#pragma unroll
        for (int half = 0; half < 2; ++half) {       // kb = dg*2 + half
            alignas(16) unsigned short hv[8], mv[8], lv[8];
#pragma unroll
            for (int j = 0; j < 8; ++j) {
                float v = srcA[(size_t)(half * 8 + j) << 10];   // coalesced
                unsigned short h = f2bf(v);
                float r1 = v - bf2f(h);
                unsigned short m = f2bf(r1);
                unsigned short l = f2bf(r1 - bf2f(m));
                hv[j] = h; mv[j] = m; lv[j] = l;
            }
            int u = ((mt * 8 + dg * 2 + half) << 8) + mi * 16;
            *(uint4*)(As + u)         = *(uint4*)hv;            // plane h
            *(uint4*)(As + 8192 + u)  = *(uint4*)mv;            // plane m
            *(uint4*)(As + 16384 + u) = *(uint4*)lv;            // plane l
        }
    }
    // stage e_sq (8 floats/thread)
    {
        float4 e0 = *(const float4*)(esq + tid * 8);
        float4 e1 = *(const float4*)(esq + tid * 8 + 4);
        *(float4*)(esqS + tid * 8)     = e0;
        *(float4*)(esqS + tid * 8 + 4) = e1;
    }
    __syncthreads();

    // ---- A fragments -> VGPRs: ALL 4 mtiles per wave (96 regs resident) ----
    bf16x8 af[3][4][2];
#pragma unroll
    for (int pl = 0; pl < 3; ++pl)
#pragma unroll
        for (int mt = 0; mt < 4; ++mt)
#pragma unroll
            for (int ks = 0; ks < 2; ++ks)
                af[pl][mt][ks] = *(const bf16x8*)(As + pl * 8192
                    + ((mt * 8 + ks * 4 + quad) << 8) + col * 16);
    __syncthreads();   // all waves done reading As before epilogue reuses it

    float best[4][4];
    int   bidx[4][4];
#pragma unroll
    for (int mt = 0; mt < 4; ++mt)
#pragma unroll
        for (int r = 0; r < 4; ++r) { best[mt][r] = 3.4e38f; bidx[mt][r] = 0; }

    const char* BgB = (const char*)Bg;

    // pre-loop B loads for tile 0, in consumption order (planes 2, 0, 1)
    bf16x8 bfr[3][2][2];
    LOAD_B(2, 0)
    LOAD_B(0, 0)
    LOAD_B(1, 0)

    for (int it = 0; it < 16; ++it) {
        const int itn = (it + 1) & 15;   // wrap: iter15 prefetch harmlessly reloads tile 0

        f32x4 acc[4][2];
#pragma unroll
        for (int mt = 0; mt < 4; ++mt)
#pragma unroll
            for (int nt = 0; nt < 2; ++nt) acc[mt][nt] = {0.f, 0.f, 0.f, 0.f};

        // 6 passes small->large; each plane's next-iter load right after
        // its last use (same regs, WAR resolved at issue, ~600 cyc to land)
        DO_PASS(0, 2)      // hl   (last use of B2)
        LOAD_B(2, itn)
        DO_PASS(2, 0)      // lh
        DO_PASS(1, 1)      // mm
        DO_PASS(0, 1)      // hm   (last use of B1)
        LOAD_B(1, itn)
        DO_PASS(1, 0)      // mh
        DO_PASS(0, 0)      // hh   (last use of B0)
        LOAD_B(0, itn)

        // running argmin in the B0-load shadow; n strictly ascends across it
#pragma unroll
        for (int nt = 0; nt < 2; ++nt) {
            const int n = it * 128 + wn * 32 + nt * 16 + col;
            const float e = esqS[n];
#pragma unroll
            for (int mt = 0; mt < 4; ++mt)
#pragma unroll
                for (int r = 0; r < 4; ++r) {
                    float d = fmaf(-2.f, acc[mt][nt][r], e);
                    if (d < best[mt][r]) { best[mt][r] = d; bidx[mt][r] = n; }
                }
        }
    }

    // ---- reduce: shfl over 16 cols, then LDS over the 4 wn quarters ----
    float* redD = (float*)As;            // [64][4]
    int*   redI = (int*)(As + 1024);     // [64][4]
    int*   idxF = (int*)(As + 2048);     // [64]
#pragma unroll
    for (int mt = 0; mt < 4; ++mt)
#pragma unroll
        for (int r = 0; r < 4; ++r) {
            float d = best[mt][r];
            int   i = bidx[mt][r];
#pragma unroll
            for (int m = 1; m < 16; m <<= 1) {
                float od = __shfl_xor(d, m, 16);
                int   oi = __shfl_xor(i, m, 16);
                if (od < d || (od == d && oi < i)) { d = od; i = oi; }
            }
            if (col == 0) {
                int row = mt * 16 + quad * 4 + r;    // pixel in block
                redD[row * 4 + wn] = d;
                redI[row * 4 + wn] = i;
            }
        }
    __syncthreads();

    if (tid < 64) {
        float bd = redD[tid * 4]; int bi = redI[tid * 4];
#pragma unroll
        for (int w = 1; w < 4; ++w) {
            float d = redD[tid * 4 + w]; int i = redI[tid * 4 + w];
            if (d < bd || (d == bd && i < bi)) { bd = d; bi = i; }
        }
        out0[bx * 64 + tid] = (float)bi;
        idxF[tid] = bi;
    }
    __syncthreads();

    // ---- fused gather: 64 px x 64 dims from the ORIGINAL fp32 codebook ----
    const int p = tid & 63, dg = tid >> 6;
    const int idx = idxF[p];
    const float4* srcr = (const float4*)(cb + ((size_t)idx << 6) + dg * 16);
    float* o = out1 + (size_t)bb * 65536 + (size_t)dg * 16384 + hw0 + p;
#pragma unroll
    for (int q = 0; q < 4; ++q) {
        float4 v = srcr[q];
        o[(size_t)(q * 4 + 0) << 10] = v.x;
        o[(size_t)(q * 4 + 1) << 10] = v.y;
        o[(size_t)(q * 4 + 2) << 10] = v.z;
        o[(size_t)(q * 4 + 3) << 10] = v.w;
    }
}

// ---------------------------------------------------------------------------
extern "C" void kernel_launch(void* const* d_in, const int* in_sizes, int n_in,
                              void* d_out, int out_size, void* d_ws, size_t ws_size,
                              hipStream_t stream) {
    const float* laten = (const float*)d_in[0];   // (32,64,32,32) fp32
    const float* cb    = (const float*)d_in[1];   // (2048,64) fp32

    float* out0 = (float*)d_out;                  // indices as float, N_PIX
    float* out1 = (float*)d_out + N_PIX;          // quant_laten, 2M

    // ws layout: esq 8 KB | Bg 768 KB   (~776 KB total)
    float* esq = (float*)d_ws;
    unsigned short* Bg = (unsigned short*)(esq + 2048);

    convert_b_kernel<<<8, 256, 0, stream>>>(cb, Bg, esq);

    dist_fused_kernel<<<512, 256, 0, stream>>>(laten, Bg, esq, cb, out0, out1);
}

// Round 10
// 106.854 us; speedup vs baseline: 1.7228x; 1.0100x over previous
//
#include <hip/hip_runtime.h>

// Problem constants (fixed by reference: B=32,D=64,H=32,W=32,K=2048)
#define N_PIX 32768   // B*H*W
#define DIM   64
#define KCODE 2048

typedef __attribute__((ext_vector_type(8))) short bf16x8;   // 8 bf16 = 4 VGPR
typedef __attribute__((ext_vector_type(4))) float f32x4;    // MFMA C/D

// bf16 round-to-nearest-even (manual, deterministic)
__device__ inline unsigned short f2bf(float v) {
    unsigned int u = __float_as_uint(v);
    return (unsigned short)((u + 0x7FFFu + ((u >> 16) & 1u)) >> 16);
}
__device__ inline float bf2f(unsigned short b) {
    return __uint_as_float(((unsigned int)b) << 16);
}

// ---------------------------------------------------------------------------
// convert_b: split codebook into 3 bf16 planes (fragment-major 256B units
// [n 0..15][j 0..7]) + e_sq. 8 blocks x 256 thr. e = h+m+l, err ~2^-27|e|.
// ---------------------------------------------------------------------------
__global__ __launch_bounds__(256)
void convert_b_kernel(const float* __restrict__ cb, unsigned short* __restrict__ Bg,
                      float* __restrict__ esq) {
    const int n = blockIdx.x * 256 + threadIdx.x;   // code id 0..2047
    const float* src = cb + (size_t)n * DIM;
    const int ntile = n >> 4, ni = n & 15;
    char* outb = (char*)Bg;
    float s = 0.f;
#pragma unroll
    for (int kb = 0; kb < 8; ++kb) {
        alignas(16) unsigned short hv[8], mv[8], lv[8];
#pragma unroll
        for (int j = 0; j < 8; ++j) {
            float v = src[kb * 8 + j];
            s = fmaf(v, v, s);
            unsigned short h = f2bf(v);
            float r1 = v - bf2f(h);
            unsigned short m = f2bf(r1);
            unsigned short l = f2bf(r1 - bf2f(m));
            hv[j] = h; mv[j] = m; lv[j] = l;
        }
        size_t u = ((((size_t)ntile) * 8 + kb) << 8) + ni * 16;
        *(uint4*)(outb + u)          = *(uint4*)hv;      // plane stride 256 KB
        *(uint4*)(outb + 262144 + u) = *(uint4*)mv;
        *(uint4*)(outb + 524288 + u) = *(uint4*)lv;
    }
    esq[n] = s;
}

// MFMA pass with LITERAL plane indices (SROA lesson: no array[array[i]]).
#define DO_PASS(APL, BPL)                                                    \
    _Pragma("unroll") for (int ks = 0; ks < 2; ++ks)                         \
    _Pragma("unroll") for (int mt = 0; mt < 2; ++mt)                         \
        acc[mt] = __builtin_amdgcn_mfma_f32_16x16x32_bf16(                   \
            af[APL][mt][ks], bfr[BPL][ks], acc[mt], 0, 0, 0);

// Load one B plane's 2 fragments (one ntile) into bfr[PL] — same regs each
// iter (zero-register pipeline), issued right after PL's last MFMA use.
#define LOAD_B(PL, NTILE)                                                    \
    _Pragma("unroll") for (int ks = 0; ks < 2; ++ks)                         \
        bfr[PL][ks] = *(const bf16x8*)(BgB + (PL) * 262144                   \
            + (size_t)(NTILE) * 2048 + ks * 1024 + lane * 16);

// ---------------------------------------------------------------------------
// Fused dist+argmin+gather. Grid 512, block 512 = 8 waves (wm: 32-px half,
// wn: 512-code quarter). Block owns 64 px x all 2048 codes.
//   r9 lesson: 2 waves/SIMD can't hide the argmin tail + load latency
//   (MfmaUtil stuck at 38% regardless of load placement). This round the
//   per-wave register footprint is cut to ~110 (af 48 + bfr 24 + acc 8 +
//   best/bidx 16) so 4 waves/SIMD fit (occupancy steps at VGPR 128 — m69).
//   Traffic unchanged: wm-pair waves read identical B frags (L1 absorbs).
//   - 32 iters x 1 ntile (16 codes): B frags direct from L2, plane-rotation
//     prefetch (B2 after pass1, B1 after pass4, B0 after pass6).
//   - 6 bf16 passes (hl,lh,mm,hm,mh,hh small->large): exact to ~2^-35.
//   - argmin: per-lane running best (n ascending -> strict <), shfl-16
//     col-reduce, LDS wn-reduce, lex (d,idx) = numpy first-min.
// ---------------------------------------------------------------------------
__global__ __launch_bounds__(512, 4)
void dist_fused_kernel(const float* __restrict__ laten,
                       const unsigned short* __restrict__ Bg,
                       const float* __restrict__ esq,
                       const float* __restrict__ cb,
                       float* __restrict__ out0, float* __restrict__ out1) {
    __shared__ char  As[24576];     // A staging (3 planes x 8 KB); then scratch
    __shared__ float esqS[2048];    // 8 KB

    const int tid  = threadIdx.x;
    const int lane = tid & 63;
    const int wave = tid >> 6;                       // 0..7
    const int wm   = wave & 1;                       // 32-px half
    const int wn   = wave >> 1;                      // 512-code quarter
    const int quad = lane >> 4, col = lane & 15;
    const int bx = blockIdx.x;
    const int bb = bx >> 4, hw0 = (bx & 15) * 64;    // 64 px contiguous in hw

    // ---- stage A into As: 8 fp32 dims (one kb unit) of pixel (tid&63) ----
    {
        const int p = tid & 63, dg = tid >> 6;       // dg 0..7 = kb unit
        const float* srcA = laten + (size_t)bb * 65536 + (size_t)dg * 8192 + hw0 + p;
        const int mt = p >> 4, mi = p & 15;
        alignas(16) unsigned short hv[8], mv[8], lv[8];
#pragma unroll
        for (int j = 0; j < 8; ++j) {
            float v = srcA[(size_t)j << 10];         // coalesced across p
            unsigned short h = f2bf(v);
            float r1 = v - bf2f(h);
            unsigned short m = f2bf(r1);
            unsigned short l = f2bf(r1 - bf2f(m));
            hv[j] = h; mv[j] = m; lv[j] = l;
        }
        int u = ((mt * 8 + dg) << 8) + mi * 16;
        *(uint4*)(As + u)         = *(uint4*)hv;     // plane h
        *(uint4*)(As + 8192 + u)  = *(uint4*)mv;     // plane m
        *(uint4*)(As + 16384 + u) = *(uint4*)lv;     // plane l
    }
    // stage e_sq (4 floats/thread)
    *(float4*)(esqS + tid * 4) = *(const float4*)(esq + tid * 4);
    __syncthreads();

    // ---- A fragments -> VGPRs: wave's 32-px half (48 regs resident) ----
    bf16x8 af[3][2][2];
#pragma unroll
    for (int pl = 0; pl < 3; ++pl)
#pragma unroll
        for (int mt = 0; mt < 2; ++mt)
#pragma unroll
            for (int ks = 0; ks < 2; ++ks)
                af[pl][mt][ks] = *(const bf16x8*)(As + pl * 8192
                    + (((wm * 2 + mt) * 8 + ks * 4 + quad) << 8) + col * 16);
    __syncthreads();   // all waves done reading As before epilogue reuses it

    float best[2][4];
    int   bidx[2][4];
#pragma unroll
    for (int mt = 0; mt < 2; ++mt)
#pragma unroll
        for (int r = 0; r < 4; ++r) { best[mt][r] = 3.4e38f; bidx[mt][r] = 0; }

    const char* BgB = (const char*)Bg;
    const int nt0 = wn * 32;                         // wave's first ntile

    // pre-loop B loads for ntile nt0, in consumption order (planes 2, 0, 1)
    bf16x8 bfr[3][2];
    LOAD_B(2, nt0)
    LOAD_B(0, nt0)
    LOAD_B(1, nt0)

    for (int it = 0; it < 32; ++it) {
        const int ntn = nt0 + ((it + 1) & 31);       // wrap: harmless reload

        f32x4 acc[2];
#pragma unroll
        for (int mt = 0; mt < 2; ++mt) acc[mt] = {0.f, 0.f, 0.f, 0.f};

        // 6 passes small->large; each plane's next-iter load right after
        // its last use (same regs; lands during the following passes)
        DO_PASS(0, 2)      // hl   (last use of B2)
        LOAD_B(2, ntn)
        DO_PASS(2, 0)      // lh
        DO_PASS(1, 1)      // mm
        DO_PASS(0, 1)      // hm   (last use of B1)
        LOAD_B(1, ntn)
        DO_PASS(1, 0)      // mh
        DO_PASS(0, 0)      // hh   (last use of B0)
        LOAD_B(0, ntn)

        // running argmin in the B0-load shadow; n strictly ascends across it
        const int n = wn * 512 + it * 16 + col;
        const float e = esqS[n];
#pragma unroll
        for (int mt = 0; mt < 2; ++mt)
#pragma unroll
            for (int r = 0; r < 4; ++r) {
                float d = fmaf(-2.f, acc[mt][r], e);
                if (d < best[mt][r]) { best[mt][r] = d; bidx[mt][r] = n; }
            }
    }

    // ---- reduce: shfl over 16 cols, then LDS over the 4 wn quarters ----
    float* redD = (float*)As;            // [64][4]
    int*   redI = (int*)(As + 1024);     // [64][4]
    int*   idxF = (int*)(As + 2048);     // [64]
#pragma unroll
    for (int mt = 0; mt < 2; ++mt)
#pragma unroll
        for (int r = 0; r < 4; ++r) {
            float d = best[mt][r];
            int   i = bidx[mt][r];
#pragma unroll
            for (int m = 1; m < 16; m <<= 1) {
                float od = __shfl_xor(d, m, 16);
                int   oi = __shfl_xor(i, m, 16);
                if (od < d || (od == d && oi < i)) { d = od; i = oi; }
            }
            if (col == 0) {
                int row = wm * 32 + mt * 16 + quad * 4 + r;   // pixel in block
                redD[row * 4 + wn] = d;
                redI[row * 4 + wn] = i;
            }
        }
    __syncthreads();

    if (tid < 64) {
        float bd = redD[tid * 4]; int bi = redI[tid * 4];
#pragma unroll
        for (int w = 1; w < 4; ++w) {
            float d = redD[tid * 4 + w]; int i = redI[tid * 4 + w];
            if (d < bd || (d == bd && i < bi)) { bd = d; bi = i; }
        }
        out0[bx * 64 + tid] = (float)bi;
        idxF[tid] = bi;
    }
    __syncthreads();

    // ---- fused gather: 64 px x 64 dims from the ORIGINAL fp32 codebook ----
    const int p = tid & 63, dg = tid >> 6;           // dg: 8 dims each
    const int idx = idxF[p];
    const float4* srcr = (const float4*)(cb + ((size_t)idx << 6) + dg * 8);
    float* o = out1 + (size_t)bb * 65536 + (size_t)dg * 8192 + hw0 + p;
    float4 v0 = srcr[0], v1 = srcr[1];
    o[0 << 10] = v0.x; o[1 << 10] = v0.y; o[2 << 10] = v0.z; o[3 << 10] = v0.w;
    o[(size_t)(4) << 10] = v1.x; o[(size_t)(5) << 10] = v1.y;
    o[(size_t)(6) << 10] = v1.z; o[(size_t)(7) << 10] = v1.w;
}

// ---------------------------------------------------------------------------
extern "C" void kernel_launch(void* const* d_in, const int* in_sizes, int n_in,
                              void* d_out, int out_size, void* d_ws, size_t ws_size,
                              hipStream_t stream) {
    const float* laten = (const float*)d_in[0];   // (32,64,32,32) fp32
    const float* cb    = (const float*)d_in[1];   // (2048,64) fp32

    float* out0 = (float*)d_out;                  // indices as float, N_PIX
    float* out1 = (float*)d_out + N_PIX;          // quant_laten, 2M

    // ws layout: esq 8 KB | Bg 768 KB   (~776 KB total)
    float* esq = (float*)d_ws;
    unsigned short* Bg = (unsigned short*)(esq + 2048);

    convert_b_kernel<<<8, 256, 0, stream>>>(cb, Bg, esq);

    dist_fused_kernel<<<512, 512, 0, stream>>>(laten, Bg, esq, cb, out0, out1);
}